// Round 1
// 97.942 us; speedup vs baseline: 1.0099x; 1.0099x over previous
//
#include <hip/hip_runtime.h>
#include <math.h>

#define BS 32
#define KP 1000
#define KPP 1024         // padded rows per image (zero rows 1000..1023)
#define KG 100
#define NC 80
#define SK 104           // global row stride in shorts: 96 bf16 alpha (80+16 pad) + 8 shorts = float4 (mx,my,vx,vy)
#define LP 104           // LDS row stride in shorts == SK -> qq tile stage is a flat 26,624 B DMA copy
#define PQS 98           // pq LDS row stride in shorts: 49 words, 49%32=17 coprime 32 -> conflict-free u16 gather
#define NT 8             // ceil(KP/128)
#define NIT 15           // (it,half) pairs per image: (0,0),(0,1)...(6,1),(7,0)
#define NQQ (BS * NIT)   // 480 qq blocks (dispatched FIRST), each streams 1..4 jt tiles
#define NPPQ (5 * BS)    // 160 pp/pq blocks (dispatched last -> fill the tail)
#define NALL (NQQ + NPPQ)
#define NPERIMG 20       // 15 qq + 5 ppq blocks per image
// acc layout (floats): image b slot at b*16 (64 B line): [0]=pq [1]=pp [2]=qq [4]=img counter
// global counter at acc[512] (own line). Zeroed range: acc[0..767].
#define GCNT 512

using bf16x8 = __attribute__((ext_vector_type(8))) short;
using f32x4  = __attribute__((ext_vector_type(4))) float;
using f32x2  = __attribute__((ext_vector_type(2))) float;

__device__ __forceinline__ float wave_reduce_sum(float v) {
#pragma unroll
    for (int m = 32; m > 0; m >>= 1) v += __shfl_xor(v, m, 64);
    return v;
}
__device__ __forceinline__ float wave_reduce_max(float v) {
#pragma unroll
    for (int m = 32; m > 0; m >>= 1) v = fmaxf(v, __shfl_xor(v, m, 64));
    return v;
}

__device__ __forceinline__ unsigned short f2bf(float f) {   // RN-even
    unsigned int u = __float_as_uint(f);
    u += 0x7fffu + ((u >> 16) & 1u);
    return (unsigned short)(u >> 16);
}
__device__ __forceinline__ float bf2f(unsigned short h) {
    return __uint_as_float(((unsigned int)h) << 16);
}

// K_ij = N(m_i; m_j, v_i+v_j), diagonal 2-D. a,b = (mx, my, vx, vy)
__device__ __forceinline__ float kval(float4 a, float4 b) {
    f32x2 S = (f32x2){a.z, a.w} + (f32x2){b.z, b.w};
    f32x2 d = (f32x2){a.x, a.y} - (f32x2){b.x, b.y};
    f32x2 d2 = d * d;
    f32x2 t = d2 * S.yx;                 // dx^2*Sy , dy^2*Sx
    float num = t.x + t.y;
    float P = S.x * S.y;
    float rs = __builtin_amdgcn_rsqf(P);
    float q = num * rs * rs;             // num * rcp(P)
    return 0.15915494309189535f * rs * __expf(-0.5f * q);
}

// Async flat copy of one 128-row tile (128 * 208 B = 26,624 B = 1664 x 16 B), global -> LDS.
// Dest is wave-uniform base + lane*16 (rows are exactly 13 x 16 B, so the copy is lane-linear
// on both sides) -> global_load_lds-legal. Counts on vmcnt; __syncthreads() drains it.
__device__ __forceinline__ void stage16(short* dst, const unsigned short* src, int tid) {
#pragma unroll
    for (int k = 0; k < 6; ++k) {
        int o = (tid + k * 256) * 16;
        __builtin_amdgcn_global_load_lds(
            (const __attribute__((address_space(1))) unsigned int*)((const char*)src + o),
            (__attribute__((address_space(3))) unsigned int*)((char*)dst + o), 16, 0, 0);
    }
    if (tid < 128) {                     // tail: chunks 1536..1663 (waves 0,1 only, wave-uniform)
        int o = (1536 + tid) * 16;
        __builtin_amdgcn_global_load_lds(
            (const __attribute__((address_space(1))) unsigned int*)((const char*)src + o),
            (__attribute__((address_space(3))) unsigned int*)((char*)dst + o), 16, 0, 0);
    }
}

// alpha[row][c] = sigmoid(l[80]) * softmax(l[0..79]) -> bf16, rows padded to 1024/image.
// NEW: also packs the row's (mx,my,vx,vy) float4 into shorts 96..103, so main_kernel's
// tile stage is a flat copy. One wave per row. Block 0 zeroes acc[768].
__global__ __launch_bounds__(256) void alpha_kernel(const float* __restrict__ pl,
                                                    const float* __restrict__ pbb,
                                                    unsigned short* __restrict__ ah,
                                                    float* __restrict__ acc) {
    if (blockIdx.x == 0) {
#pragma unroll
        for (int k = 0; k < 3; ++k) acc[threadIdx.x + 256 * k] = 0.0f;
    }
    int wave = threadIdx.x >> 6;
    int lane = threadIdx.x & 63;
    int rr = blockIdx.x * 4 + wave;                   // < BS*KPP = 32768
    int b = rr >> 10, r = rr & (KPP - 1);
    unsigned short* oh = ah + (size_t)rr * SK;
    if (r < KP) {
        const float* x = pl + ((size_t)b * KP + r) * (NC + 1);
        float l0 = x[lane];
        float l1 = (lane < 16) ? x[64 + lane] : -1e30f;
        float obj = x[NC];
        float m = wave_reduce_max(fmaxf(l0, l1));
        float e0 = __expf(l0 - m);
        float e1 = (lane < 16) ? __expf(l1 - m) : 0.0f;
        float s = wave_reduce_sum(e0 + e1);
        float sig = 1.0f / (1.0f + __expf(-obj));
        float sc = sig / s;
        oh[lane] = f2bf(e0 * sc);
        if (lane < 32) oh[64 + lane] = (lane < 16) ? f2bf(e1 * sc) : 0;
        if (lane == 0) {
            float4 xb = ((const float4*)pbb)[b * KP + r];
            *(float4*)(oh + 96) = make_float4(xb.x, xb.y, 0.25f * xb.z * xb.z, 0.25f * xb.w * xb.w);
        }
    } else {
        oh[lane] = 0;
        if (lane < 32) oh[64 + lane] = 0;
        if (lane == 0) *(float4*)(oh + 96) = make_float4(0.0f, 0.0f, 1.0f, 1.0f);
    }
}

// Single main dispatch.
// Blocks [0,NQQ): qq. Block (b, it, half) DMA-stages its A-tile ONCE (flat 26.6 KB
// global_load_lds copy, params embedded), then streams B-tiles jt = it+half, +2, ... < 8,
// doing the 128x128 MFMA Gram + kval epilogue per tile (off-diag x2).
// Blocks [NQQ,NALL): pp/pq with alpha rows staged at stride-98 (conflict-free gather).
// Per-image 64B accumulator slots + hierarchical counters.
__global__ __launch_bounds__(256, 3) void main_kernel(const float* __restrict__ pb,
                                                      const unsigned short* __restrict__ ahg,
                                                      const float* __restrict__ gtb,
                                                      const int* __restrict__ gtl,
                                                      float* __restrict__ acc,
                                                      float* __restrict__ out) {
    __shared__ short lds[2 * 128 * LP];   // 53,248 B, carved per path
    __shared__ float red[4];
    __shared__ int last;

    int tid = threadIdx.x;
    int lane = tid & 63, w = tid >> 6;
    int bi = blockIdx.x;
    int b;

    if (bi < NQQ) {
        // ---------------- qq path ----------------
        short* la = lds;
        short* lb = lds + 128 * LP;
        b = bi & 31;                     // consecutive blocks spread images -> XCD locality
        int p = bi >> 5;                 // 0..14
        int it = p >> 1, half = p & 1;
        const unsigned short* abase = ahg + (size_t)(b << 10) * SK;

        stage16(la, abase + (size_t)(it * 128) * SK, tid);    // async DMA, in flight

        int wy = w >> 1, wx = w & 1;
        int m15 = lane & 15, quad = lane >> 4;
        int ar = wy * 64 + m15;
        int br = wx * 64 + m15;
        int jb = wx * 64 + m15;
        int ib = wy * 64 + quad * 4;

        float part = 0.0f;
        bool first = true;
        for (int jt = it + half; jt < NT; jt += 2) {
            if (!first) __syncthreads();     // previous tile's lb readers done
            stage16(lb, abase + (size_t)(jt * 128) * SK, tid);  // async DMA
            __syncthreads();                 // drains vmcnt before s_barrier -> la+lb visible

            f32x4 c4[4][4];
#pragma unroll
            for (int r = 0; r < 4; ++r)
#pragma unroll
                for (int s = 0; s < 4; ++s) c4[r][s] = (f32x4){0.0f, 0.0f, 0.0f, 0.0f};

#pragma unroll
            for (int ks = 0; ks < 3; ++ks) {
                int kk = ks * 32 + quad * 8;
                bf16x8 bh[4];
#pragma unroll
                for (int cg = 0; cg < 4; ++cg)
                    bh[cg] = *(const bf16x8*)(lb + (br + cg * 16) * LP + kk);
#pragma unroll
                for (int rg = 0; rg < 4; ++rg) {
                    bf16x8 xh = *(const bf16x8*)(la + (ar + rg * 16) * LP + kk);
#pragma unroll
                    for (int cg = 0; cg < 4; ++cg)
                        c4[rg][cg] = __builtin_amdgcn_mfma_f32_16x16x32_bf16(xh, bh[cg], c4[rg][cg], 0, 0, 0);
                }
            }

            // epilogue: C/D layout col=lane&15 (b-side), row=quad*4+reg (a-side)
            float4 pj[4];
#pragma unroll
            for (int cg = 0; cg < 4; ++cg)
                pj[cg] = *(const float4*)(lb + (jb + cg * 16) * LP + 96);
            float tpart = 0.0f;
#pragma unroll
            for (int rg = 0; rg < 4; ++rg) {
#pragma unroll
                for (int e = 0; e < 4; ++e) {
                    float4 pi = *(const float4*)(la + (ib + rg * 16 + e) * LP + 96);
#pragma unroll
                    for (int cg = 0; cg < 4; ++cg)
                        tpart += c4[rg][cg][e] * kval(pi, pj[cg]);
                }
            }
            part += (jt != it) ? 2.0f * tpart : tpart;
            first = false;
        }

        part = wave_reduce_sum(part);
        if (lane == 0) red[w] = part;
        __syncthreads();
        if (tid == 0)
            atomicAdd(&acc[b * 16 + 2], red[0] + red[1] + red[2] + red[3]);  // no return use
    } else {
        // ---------------- pp / pq path ----------------
        int pi = bi - NQQ;
        b = pi & 31;
        int p5 = pi >> 5;                // 0..3 = pq chunks, 4 = pp
        short* lalpha = lds;                        // 256 rows x PQS shorts = 50,176 B
        float4* gm = (float4*)(lds + 25088);        // byte 50,176 (16B-aligned), 1600 B
        int* gl = (int*)(lds + 25088 + 800);        // byte 51,776, 400 B
        if (tid < KG) {
            float4 x = ((const float4*)gtb)[b * KG + tid];
            gm[tid] = make_float4(x.x, x.y, 0.25f * x.z * x.z, 0.25f * x.w * x.w);
            gl[tid] = gtl[b * KG + tid];
        }
        if (p5 < 4) {
            // stage 256 alpha rows (skip the param chunk, slot 12 of 13) at stride PQS=98.
            // rows only 4B-aligned at this stride -> write as 4x b32.
            const float4* sa = (const float4*)(ahg + ((size_t)(b << 10) + p5 * 256) * SK);
#pragma unroll
            for (int k = 0; k < 12; ++k) {
                int o = tid + k * 256;               // < 3072
                int row = o / 12, slot = o - row * 12;
                float4 x = sa[row * 13 + slot];
                float* dstf = (float*)(lalpha + row * PQS + slot * 8);
                dstf[0] = x.x; dstf[1] = x.y; dstf[2] = x.z; dstf[3] = x.w;
            }
        }
        __syncthreads();
        float part = 0.0f;
        if (p5 < 4) {
            int j = p5 * 256 + tid;
            if (j < KP) {
                float4 x = ((const float4*)pb)[b * KP + j];
                float4 pm = make_float4(x.x, x.y, 0.25f * x.z * x.z, 0.25f * x.w * x.w);
                const unsigned short* arow = (const unsigned short*)(lalpha + tid * PQS);
#pragma unroll 4
                for (int i = 0; i < KG; ++i) {
                    part += bf2f(arow[gl[i]]) * kval(gm[i], pm);
                }
            }
        } else {
            for (int p = tid; p < KG * KG; p += 256) {
                int i = p / KG;
                int j = p - i * KG;
                if (gl[i] == gl[j]) part += kval(gm[i], gm[j]);
            }
        }
        part = wave_reduce_sum(part);
        if (lane == 0) red[w] = part;
        __syncthreads();
        if (tid == 0) {
            float s = red[0] + red[1] + red[2] + red[3];
            atomicAdd(&acc[b * 16 + ((p5 < 4) ? 0 : 1)], s);   // no return use
        }
    }

    // ---------------- hierarchical finalize ----------------
    if (tid == 0) {
        __threadfence();
        unsigned int o = atomicAdd((unsigned int*)(acc + b * 16 + 4), 1u);
        int l = 0;
        if (o == NPERIMG - 1) {          // this image complete
            __threadfence();
            unsigned int g = atomicAdd((unsigned int*)(acc + GCNT), 1u);
            l = (g == BS - 1) ? 1 : 0;   // all images complete
        }
        last = l;
    }
    __syncthreads();
    if (last && tid < 64) {
        float v = 0.0f;
        if (tid < BS) {
            float pq = atomicAdd(&acc[tid * 16 + 0], 0.0f);   // coherent reads
            float pp = atomicAdd(&acc[tid * 16 + 1], 0.0f);
            float qq = atomicAdd(&acc[tid * 16 + 2], 0.0f);
            v = 2.0f * logf(pq) - logf(pp) - logf(qq);
        }
        v = wave_reduce_sum(v);
        if (tid == 0) out[0] = -v;
    }
}

extern "C" void kernel_launch(void* const* d_in, const int* in_sizes, int n_in,
                              void* d_out, int out_size, void* d_ws, size_t ws_size,
                              hipStream_t stream) {
    (void)in_sizes; (void)n_in; (void)out_size; (void)ws_size;
    const float* pred_bb  = (const float*)d_in[0];
    const float* pred_lab = (const float*)d_in[1];
    const float* gt_bb    = (const float*)d_in[2];
    const int*   gt_lab   = (const int*)d_in[3];
    float* out = (float*)d_out;

    unsigned short* ah = (unsigned short*)d_ws;            // 32768*104*2 B = 6.82 MB
    float* acc = (float*)(ah + (size_t)BS * KPP * SK);     // per-image slots + counters

    hipLaunchKernelGGL(alpha_kernel, dim3(BS * KPP / 4), dim3(256), 0, stream,
                       pred_lab, pred_bb, ah, acc);
    hipLaunchKernelGGL(main_kernel, dim3(NALL), dim3(256), 0, stream,
                       pred_bb, ah, gt_bb, gt_lab, acc, out);
}